// Round 7
// baseline (242.118 us; speedup 1.0000x reference)
//
#include <hip/hip_runtime.h>
#include <math.h>

#define N 1024
#define BATCH 32
#define NT 256
#define ROWS 4

// wave-local LDS ordering
#define WSYNC() asm volatile("s_waitcnt lgkmcnt(0)" ::: "memory")

typedef float2 cf;
__device__ __forceinline__ cf cadd(cf a, cf b){ return make_float2(a.x+b.x, a.y+b.y); }
__device__ __forceinline__ cf csub(cf a, cf b){ return make_float2(a.x-b.x, a.y-b.y); }
__device__ __forceinline__ cf cmul(cf a, cf b){ return make_float2(a.x*b.x - a.y*b.y, a.x*b.y + a.y*b.x); }

// exp(-2*pi*i*jn), jn in revolutions (v_sin/v_cos take revolutions)
__device__ __forceinline__ cf twiddle(float jn){
    float s = __builtin_amdgcn_sinf(jn);
    float c = __builtin_amdgcn_cosf(jn);
    return make_float2(c, -s);
}

// radix-4 DIF butterfly core
__device__ __forceinline__ void bfly(cf x0, cf x1, cf x2, cf x3,
                                     cf& y0, cf& y1, cf& y2, cf& y3){
    cf A = cadd(x0,x2), Bs = cadd(x1,x3);
    cf C = csub(x0,x2), D = csub(x1,x3);
    cf Dmi = make_float2(D.y, -D.x);
    y0 = cadd(A,Bs); y1 = cadd(C,Dmi); y2 = csub(A,Bs); y3 = csub(C,Dmi);
}

// ---------------------------------------------------------------------------
// hconv_k: analytic signal by DIRECT CIRCULAR CONVOLUTION (no FFT).
// (round-5 verified, absmax 0; unchanged)
// ---------------------------------------------------------------------------
__global__ __launch_bounds__(64) void hconv_k(const float* __restrict__ pred,
                                              const float* __restrict__ label,
                                              cf* __restrict__ a,
                                              cf* __restrict__ ca,
                                              float* __restrict__ mseP) {
    __shared__ float xe[512], xo[512], C2[1024];
    int l = threadIdx.x, blk = blockIdx.x;
    int b = blk >> 3, oct = blk & 7;
    const float* xr = pred + b * N;

    // ---- load row (16 floats/lane, coalesced), parity-split into LDS ----
    float4 q0 = *(const float4*)(xr + 16 * l);
    float4 q1 = *(const float4*)(xr + 16 * l + 4);
    float4 q2 = *(const float4*)(xr + 16 * l + 8);
    float4 q3 = *(const float4*)(xr + 16 * l + 12);
    *(float4*)&xe[8 * l]     = make_float4(q0.x, q0.z, q1.x, q1.z);
    *(float4*)&xe[8 * l + 4] = make_float4(q2.x, q2.z, q3.x, q3.z);
    *(float4*)&xo[8 * l]     = make_float4(q0.y, q0.w, q1.y, q1.w);
    *(float4*)&xo[8 * l + 4] = make_float4(q2.y, q2.w, q3.y, q3.w);
    float lsum = q0.x+q0.y+q0.z+q0.w + q1.x+q1.y+q1.z+q1.w
               + q2.x+q2.y+q2.z+q2.w + q3.x+q3.y+q3.z+q3.w;
    for (int o = 32; o > 0; o >>= 1) lsum += __shfl_down(lsum, o);
    float mean = __shfl(lsum, 0) * (1.f / 1024.f);

    // ---- C2 table: C2[u] = -cot(pi*(2(u&511)+1)/1024)/512 ----
#pragma unroll
    for (int k = 0; k < 16; ++k) {
        int u = l + 64 * k;
        int j = u & 511;
        float th = (float)(2 * j + 1) * (3.14159274f / 1024.f);
        C2[u] = -(cosf(th) / sinf(th)) * (1.f / 512.f);
    }
    WSYNC();   // single-wave block: lgkmcnt drain publishes LDS writes

    // ---- convolution: lane outputs n_e=2v (uses xo), n_o=2v+1 (uses xe) ----
    int v = oct * 64 + l;
    int P = v + 512;                 // biased C index base (no wrap needed)
    float acc_e = 0.f, acc_o = 0.f;
    float c_hi = C2[P];              // C for (n_o, tap 0)
    for (int c = 0; c < 128; ++c) {
        float4 xep = *(const float4*)&xe[4 * c];   // uniform broadcast
        float4 xop = *(const float4*)&xo[4 * c];
        float c0 = C2[P - 1 - 4 * c];
        float c1 = C2[P - 2 - 4 * c];
        float c2 = C2[P - 3 - 4 * c];
        float c3 = C2[P - 4 - 4 * c];
        acc_e += xop.x * c0;  acc_o += xep.x * c_hi;
        acc_e += xop.y * c1;  acc_o += xep.y * c0;
        acc_e += xop.z * c2;  acc_o += xep.z * c1;
        acc_e += xop.w * c3;  acc_o += xep.w * c2;
        c_hi = c3;
    }

    // ---- write a and ca (coalesced float4 pairs) ----
    int ne = 2 * v, no = ne + 1;
    float axe = xe[v] - mean, axo = xo[v] - mean;
    *(float4*)&a[b * N + ne] = make_float4(axe, acc_e, axo, acc_o);
    float pe = (float)(3.525 * (double)(ne - 512));
    float po = (float)(3.525 * (double)(no - 512));
    float se, cE, so_, cO;
    sincosf(pe, &se, &cE);
    sincosf(po, &so_, &cO);
    *(float4*)&ca[b * N + ne] = make_float4(axe * cE + acc_e * se, acc_e * cE - axe * se,
                                            axo * cO + acc_o * so_, acc_o * cO - axo * so_);

    // ---- fused label MSE (old hilbert_k tail), per-block partial ----
    const float* lab = label + b * 2 * N;
    int mnR = N, mxR = -1, mnI = N, mxI = -1;
#pragma unroll
    for (int k = 0; k < 16; ++k) {
        int n = l + 64 * k;
        float lr = lab[n], li = lab[N + n];
        if (fabsf(lr) > 0.01f) { mnR = min(mnR, n); mxR = max(mxR, n); }
        if (fabsf(li) > 0.01f) { mnI = min(mnI, n); mxI = max(mxI, n); }
    }
    for (int o = 32; o > 0; o >>= 1) {
        mnR = min(mnR, __shfl_down(mnR, o));
        mxR = max(mxR, __shfl_down(mxR, o));
        mnI = min(mnI, __shfl_down(mnI, o));
        mxI = max(mxI, __shfl_down(mxI, o));
    }
    mnR = __shfl(mnR, 0); mxR = __shfl(mxR, 0);
    mnI = __shfl(mnI, 0); mxI = __shfl(mxI, 0);
    int fr   = (mnR == N) ? 0 : mnR;
    int lstR = (mxR < 0) ? (N - 1) : mxR;
    int fi   = (mnI == N) ? 0 : mnI;
    int lstI = (mxI < 0) ? (N - 1) : mxI;
    int first = min(fr, fi), last = max(lstR, lstI);

    float s_lane = 0.f;
    {
        float lr = lab[ne], li = lab[N + ne];
        bool in = (ne >= first) && (ne < last);
        float pm = in ? 10.f : 1.f, phm = in ? 1.f : 0.f;
        float dr = axe - lr, di = acc_e - li;
        float dn = (axe * axe + acc_e * acc_e) - (lr * lr + li * li);
        float dp = atan2f(acc_e, axe) - atan2f(li, lr);
        s_lane += (dr * dr + di * di + dn * dn) * pm + dp * dp * phm;

        lr = lab[no]; li = lab[N + no];
        in = (no >= first) && (no < last);
        pm = in ? 10.f : 1.f; phm = in ? 1.f : 0.f;
        dr = axo - lr; di = acc_o - li;
        dn = (axo * axo + acc_o * acc_o) - (lr * lr + li * li);
        dp = atan2f(acc_o, axo) - atan2f(li, lr);
        s_lane += (dr * dr + di * di + dn * dn) * pm + dp * dp * phm;
    }
    for (int o = 32; o > 0; o >>= 1) s_lane += __shfl_down(s_lane, o);
    if (l == 0) mseP[blk] = s_lane;
}

// ---------------------------------------------------------------------------
// shg_k: one block = 4 rows, 256 threads, LDS 32768 B (5 blocks/CU).
// ROUND-7: ZERO-BARRIER wave-independent pipeline.  Wave r owns row r
// end-to-end: stage 1 (lane g does butterflies bt=g+64s, s=0..3, twiddles
// chained by T64=exp(-2*pi*i/16)), phase 2, phase 3 — all wave-local, so
// the block-wide __syncthreads (which lockstepped 4 waves behind the
// slowest wave's global loads) is replaced by WSYNC (lgkmcnt drain).
// Cost: +12 L2-resident ca loads and ~+10 cmul per lane (sharing lost);
// benefit: 20 waves/CU schedule freely across 5 independent blocks.
// Swizzle SW(i)=i^(((i>>4)&7)<<1), tv-prefetch-at-entry, setprio unchanged
// (verified R6).  Tripwires: VGPR<=102 (5 waves/SIMD), WRITE_SIZE ~1.3 MB.
// ---------------------------------------------------------------------------
__global__ __launch_bounds__(NT) void shg_k(const cf* __restrict__ a,
                                            const cf* __restrict__ cag,
                                            const float* __restrict__ tref,
                                            float* __restrict__ Praw,
                                            float* __restrict__ Prt,
                                            float* __restrict__ Pmax,
                                            float* __restrict__ Pt,
                                            float* __restrict__ Ptt) {
    __shared__ cf wk[ROWS * N];
    int t = threadIdx.x, blk = blockIdx.x;
    int b = blk >> 8;
    int dg = (blk & 255) << 2;            // delay-indices dg..dg+3
    const cf* arow  = a   + b * N;
    const cf* carow = cag + b * N;

    int r3 = t >> 6;                     // wave index = row index
    int g  = t & 63;                     // lane

    // ---- tref prefetch (at entry): 16 loads, consumed in phase 3 ----
    int bd = b * N + dg + r3;
    int kb = ((g & 3) << 4) | (g & 12) | (g >> 4);   // base-4 digit reversal of g
    const float* trow2 = tref + ((size_t)bd << 10) + kb;
    float tv[16];
#pragma unroll
    for (int u = 0; u < 4; ++u)
#pragma unroll
        for (int m = 0; m < 4; ++m)
            tv[4*u + m] = trow2[(((m + 2) & 3) << 8) | (u << 6)];

    // ---- stage 1 (q=256), wave-local: lane g does bt = g+64s for row r3 ----
    {
        int d = dg + r3;
        cf* wrow = wk + r3 * N;
        const cf T64 = { 0.923879533f, -0.382683432f };   // tw(64/1024)
        cf w1 = twiddle((float)g * (1.0f / 1024.0f));
#pragma unroll
        for (int s = 0; s < 4; ++s) {
            int bt = g + 64 * s;
            // cav[k] = carow[(bt+256k+512)&1023]
            cf cv0 = carow[bt];
            cf cv1 = carow[bt + 256];
            cf cv2 = carow[bt + 512];
            cf cv3 = carow[(bt + 768) & 1023];
            cf x0 = cmul(cv2, arow[(bt       - d) & 1023]);
            cf x1 = cmul(cv3, arow[(bt + 256 - d) & 1023]);
            cf x2 = cmul(cv0, arow[(bt + 512 - d) & 1023]);
            cf x3 = cmul(cv1, arow[(bt + 768 - d) & 1023]);
            cf y0, y1, y2, y3; bfly(x0,x1,x2,x3,y0,y1,y2,y3);
            cf w2 = cmul(w1,w1), w3 = cmul(w2,w1);
            int wb = bt ^ (((bt >> 4) & 7) << 1);         // SW(256k+bt)=256k+wb
            wrow[wb]       = y0;
            wrow[wb + 256] = cmul(y1,w1);
            wrow[wb + 512] = cmul(y2,w2);
            wrow[wb + 768] = cmul(y3,w3);
            w1 = cmul(w1, T64);
        }
    }
    WSYNC();   // stage1 -> phase2 is wave-local (wave r3 wrote row r3)

    __builtin_amdgcn_s_setprio(1);
    // ---- phase 2: fused stages q=64 and q=16, fully in registers ----
    {
        int B2 = g >> 4;                  // 256-block within row
        int v  = g & 15;                  // offset within 16-group
        cf* w = wk + r3 * N + B2 * 256;
        cf p[16];
#pragma unroll
        for (int m = 0; m < 16; ++m) p[m] = w[16*m + (v ^ ((m & 7) << 1))];
        // level A: n=256, q=64  (j = v + 16*m0); twiddle chain by tw(1/16)
        {
            const cf T16 = { 0.923879533f, -0.382683432f };   // tw(16/256)
            cf w1 = twiddle((float)v * (1.0f / 256.0f));
#pragma unroll
            for (int m0 = 0; m0 < 4; ++m0) {
                cf w2 = cmul(w1,w1), w3 = cmul(w2,w1);
                cf y0, y1, y2, y3;
                bfly(p[m0], p[m0+4], p[m0+8], p[m0+12], y0,y1,y2,y3);
                p[m0]    = y0;
                p[m0+4]  = cmul(y1,w1);
                p[m0+8]  = cmul(y2,w2);
                p[m0+12] = cmul(y3,w3);
                w1 = cmul(w1, T16);
            }
        }
        // level B: n=64, q=16  (j = v, same twiddles for all 4 groups)
        {
            cf w1 = twiddle((float)v * (1.0f / 64.0f));
            cf w2 = cmul(w1,w1), w3 = cmul(w2,w1);
#pragma unroll
            for (int s = 0; s < 4; ++s) {
                cf y0, y1, y2, y3;
                bfly(p[4*s], p[4*s+1], p[4*s+2], p[4*s+3], y0,y1,y2,y3);
                p[4*s]   = y0;
                p[4*s+1] = cmul(y1,w1);
                p[4*s+2] = cmul(y2,w2);
                p[4*s+3] = cmul(y3,w3);
            }
        }
#pragma unroll
        for (int m = 0; m < 16; ++m) w[16*m + (v ^ ((m & 7) << 1))] = p[m];
    }
    WSYNC();   // phase2 -> phase3 is wave-local (wave r3 owns row r3)

    // ---- phase 3: in-register 16-pt DFT + accumulate; wave r3 = row r3 ----
    {
        const cf W1 = { 0.923879533f, -0.382683432f};
        const cf W2 = { 0.707106781f, -0.707106781f};
        const cf W3 = { 0.382683432f, -0.923879533f};
        const cf W6 = {-0.707106781f, -0.707106781f};
        const cf W9 = {-0.923879533f,  0.382683432f};
        cf* w = wk + r3 * N + 16 * g;
        int X = (g & 7) << 1;            // swizzle XOR for this 16-group (even)
        cf v[16];
#pragma unroll
        for (int j = 0; j < 8; ++j) {    // explicit b128: pairs stay adjacent
            float4 q = *(const float4*)&w[(2*j) ^ X];
            v[2*j]   = make_float2(q.x, q.y);
            v[2*j+1] = make_float2(q.z, q.w);
        }
        cf o[16];
        bfly(v[0], v[4], v[8], v[12], o[0], o[4], o[8],  o[12]);
        { cf y0,y1,y2,y3; bfly(v[1],v[5],v[9], v[13],y0,y1,y2,y3);
          o[1]=y0; o[5]=cmul(y1,W1); o[9]=cmul(y2,W2); o[13]=cmul(y3,W3); }
        { cf y0,y1,y2,y3; bfly(v[2],v[6],v[10],v[14],y0,y1,y2,y3);
          o[2]=y0; o[6]=cmul(y1,W2); o[10]=make_float2(y2.y,-y2.x); o[14]=cmul(y3,W6); }
        { cf y0,y1,y2,y3; bfly(v[3],v[7],v[11],v[15],y0,y1,y2,y3);
          o[3]=y0; o[7]=cmul(y1,W3); o[11]=cmul(y2,W6); o[15]=cmul(y3,W9); }

        float sraw = 0.f, srt = 0.f, mx = 0.f, st = 0.f, stt = 0.f;
#pragma unroll
        for (int u = 0; u < 4; ++u) {
            cf y0, y1, y2, y3;
            bfly(o[4*u], o[4*u+1], o[4*u+2], o[4*u+3], y0, y1, y2, y3);
            cf ys[4] = {y0, y1, y2, y3};
#pragma unroll
            for (int m = 0; m < 4; ++m) {
                float m2 = ys[m].x * ys[m].x + ys[m].y * ys[m].y;
                float tvv = tv[4*u + m];
                sraw += m2;
                srt += m2 * tvv;
                mx = fmaxf(mx, m2);
                st += tvv;
                stt += tvv * tvv;
            }
        }
        __builtin_amdgcn_s_setprio(0);
        // full-wave reduction: wave r3 covers g = 0..63 = entire row r3
        for (int o_ = 32; o_ > 0; o_ >>= 1) {
            sraw += __shfl_down(sraw, o_);
            srt  += __shfl_down(srt, o_);
            mx    = fmaxf(mx, __shfl_down(mx, o_));
            st   += __shfl_down(st, o_);
            stt  += __shfl_down(stt, o_);
        }
        if (g == 0) {
            Praw[bd] = sraw; Prt[bd] = srt; Pmax[bd] = mx; Pt[bd] = st; Ptt[bd] = stt;
        }
    }
}

// ---------------------------------------------------------------------------
// loss_k: per batch — frog from row partials + mseP (8 deterministic partials)
// -> atomic mean.  (unchanged)
// ---------------------------------------------------------------------------
__global__ __launch_bounds__(256) void loss_k(const float* __restrict__ Praw,
                                              const float* __restrict__ Prt,
                                              const float* __restrict__ Pmax,
                                              const float* __restrict__ Pt,
                                              const float* __restrict__ Ptt,
                                              const float* __restrict__ mseP,
                                              float* __restrict__ out) {
    __shared__ float rbuf[4][8];
    int tid = threadIdx.x, b = blockIdx.x;
    int w = tid >> 6, lane = tid & 63;
    float sr = 0.f, srt = 0.f, mx = 0.f, st = 0.f, stt = 0.f;
    for (int i = tid; i < N; i += 256) {
        int idx = b * N + i;
        sr += Praw[idx]; srt += Prt[idx]; mx = fmaxf(mx, Pmax[idx]);
        st += Pt[idx];   stt += Ptt[idx];
    }
    for (int o = 32; o > 0; o >>= 1) {
        sr  += __shfl_down(sr, o);
        srt += __shfl_down(srt, o);
        mx   = fmaxf(mx, __shfl_down(mx, o));
        st  += __shfl_down(st, o);
        stt += __shfl_down(stt, o);
    }
    if (lane == 0) {
        rbuf[w][0] = sr; rbuf[w][1] = srt; rbuf[w][2] = mx;
        rbuf[w][3] = st; rbuf[w][4] = stt;
    }
    __syncthreads();
    if (tid == 0) {
        float A0 = 0.f, A1 = 0.f, A2 = 0.f, A3 = 0.f, A4 = 0.f;
        for (int i = 0; i < 4; ++i) {
            A0 += rbuf[i][0]; A1 += rbuf[i][1]; A2 = fmaxf(A2, rbuf[i][2]);
            A3 += rbuf[i][3]; A4 += rbuf[i][4];
        }
        float mu = (A1 / A2) / A4;
        float diff = A0 / A2 - mu * A3;
        float frog = fabsf(diff) * (1.f / (float)N);
        float ms = 0.f;
        for (int k = 0; k < 8; ++k) ms += mseP[b * 8 + k];
        ms *= (1.f / (float)N) * 0.25f;
        atomicAdd(out, (ms + frog) * (1.f / (float)BATCH));
    }
}

extern "C" void kernel_launch(void* const* d_in, const int* in_sizes, int n_in,
                              void* d_out, int out_size, void* d_ws, size_t ws_size,
                              hipStream_t stream) {
    (void)in_sizes; (void)n_in; (void)out_size; (void)ws_size;
    const float* pred  = (const float*)d_in[0];
    const float* label = (const float*)d_in[1];
    const float* shg   = (const float*)d_in[2];
    float* out = (float*)d_out;

    char* ws = (char*)d_ws;
    cf* a   = (cf*)ws;
    cf* ca  = a + (size_t)BATCH * N;
    float* mseP = (float*)(ca + (size_t)BATCH * N);      // BATCH*8 partials
    float* P = mseP + BATCH * 8;
    float* Praw = P;
    float* Prt  = P + (size_t)BATCH * N;
    float* Pmax = P + 2 * (size_t)BATCH * N;
    float* Pt   = P + 3 * (size_t)BATCH * N;
    float* Ptt  = P + 4 * (size_t)BATCH * N;

    hipMemsetAsync(d_out, 0, sizeof(float), stream);
    hconv_k<<<BATCH * 8, 64, 0, stream>>>(pred, label, a, ca, mseP);
    shg_k<<<BATCH * 256, NT, 0, stream>>>(a, ca, shg, Praw, Prt, Pmax, Pt, Ptt);
    loss_k<<<BATCH, 256, 0, stream>>>(Praw, Prt, Pmax, Pt, Ptt, mseP, out);
}

// Round 8
// 228.348 us; speedup vs baseline: 1.0603x; 1.0603x over previous
//
#include <hip/hip_runtime.h>
#include <math.h>

#define N 1024
#define BATCH 32
#define NT 256
#define ROWS 4

// wave-local LDS ordering
#define WSYNC() asm volatile("s_waitcnt lgkmcnt(0)" ::: "memory")

typedef float2 cf;
__device__ __forceinline__ cf cadd(cf a, cf b){ return make_float2(a.x+b.x, a.y+b.y); }
__device__ __forceinline__ cf csub(cf a, cf b){ return make_float2(a.x-b.x, a.y-b.y); }
__device__ __forceinline__ cf cmul(cf a, cf b){ return make_float2(a.x*b.x - a.y*b.y, a.x*b.y + a.y*b.x); }

// exp(-2*pi*i*jn), jn in revolutions (v_sin/v_cos take revolutions)
__device__ __forceinline__ cf twiddle(float jn){
    float s = __builtin_amdgcn_sinf(jn);
    float c = __builtin_amdgcn_cosf(jn);
    return make_float2(c, -s);
}

// radix-4 DIF butterfly core
__device__ __forceinline__ void bfly(cf x0, cf x1, cf x2, cf x3,
                                     cf& y0, cf& y1, cf& y2, cf& y3){
    cf A = cadd(x0,x2), Bs = cadd(x1,x3);
    cf C = csub(x0,x2), D = csub(x1,x3);
    cf Dmi = make_float2(D.y, -D.x);
    y0 = cadd(A,Bs); y1 = cadd(C,Dmi); y2 = csub(A,Bs); y3 = csub(C,Dmi);
}

// ---------------------------------------------------------------------------
// hconv_k: analytic signal by DIRECT CIRCULAR CONVOLUTION (no FFT).
// (round-5 verified, absmax 0; unchanged)
// ---------------------------------------------------------------------------
__global__ __launch_bounds__(64) void hconv_k(const float* __restrict__ pred,
                                              const float* __restrict__ label,
                                              cf* __restrict__ a,
                                              cf* __restrict__ ca,
                                              float* __restrict__ mseP) {
    __shared__ float xe[512], xo[512], C2[1024];
    int l = threadIdx.x, blk = blockIdx.x;
    int b = blk >> 3, oct = blk & 7;
    const float* xr = pred + b * N;

    // ---- load row (16 floats/lane, coalesced), parity-split into LDS ----
    float4 q0 = *(const float4*)(xr + 16 * l);
    float4 q1 = *(const float4*)(xr + 16 * l + 4);
    float4 q2 = *(const float4*)(xr + 16 * l + 8);
    float4 q3 = *(const float4*)(xr + 16 * l + 12);
    *(float4*)&xe[8 * l]     = make_float4(q0.x, q0.z, q1.x, q1.z);
    *(float4*)&xe[8 * l + 4] = make_float4(q2.x, q2.z, q3.x, q3.z);
    *(float4*)&xo[8 * l]     = make_float4(q0.y, q0.w, q1.y, q1.w);
    *(float4*)&xo[8 * l + 4] = make_float4(q2.y, q2.w, q3.y, q3.w);
    float lsum = q0.x+q0.y+q0.z+q0.w + q1.x+q1.y+q1.z+q1.w
               + q2.x+q2.y+q2.z+q2.w + q3.x+q3.y+q3.z+q3.w;
    for (int o = 32; o > 0; o >>= 1) lsum += __shfl_down(lsum, o);
    float mean = __shfl(lsum, 0) * (1.f / 1024.f);

    // ---- C2 table: C2[u] = -cot(pi*(2(u&511)+1)/1024)/512 ----
#pragma unroll
    for (int k = 0; k < 16; ++k) {
        int u = l + 64 * k;
        int j = u & 511;
        float th = (float)(2 * j + 1) * (3.14159274f / 1024.f);
        C2[u] = -(cosf(th) / sinf(th)) * (1.f / 512.f);
    }
    WSYNC();   // single-wave block: lgkmcnt drain publishes LDS writes

    // ---- convolution: lane outputs n_e=2v (uses xo), n_o=2v+1 (uses xe) ----
    int v = oct * 64 + l;
    int P = v + 512;                 // biased C index base (no wrap needed)
    float acc_e = 0.f, acc_o = 0.f;
    float c_hi = C2[P];              // C for (n_o, tap 0)
    for (int c = 0; c < 128; ++c) {
        float4 xep = *(const float4*)&xe[4 * c];   // uniform broadcast
        float4 xop = *(const float4*)&xo[4 * c];
        float c0 = C2[P - 1 - 4 * c];
        float c1 = C2[P - 2 - 4 * c];
        float c2 = C2[P - 3 - 4 * c];
        float c3 = C2[P - 4 - 4 * c];
        acc_e += xop.x * c0;  acc_o += xep.x * c_hi;
        acc_e += xop.y * c1;  acc_o += xep.y * c0;
        acc_e += xop.z * c2;  acc_o += xep.z * c1;
        acc_e += xop.w * c3;  acc_o += xep.w * c2;
        c_hi = c3;
    }

    // ---- write a and ca (coalesced float4 pairs) ----
    int ne = 2 * v, no = ne + 1;
    float axe = xe[v] - mean, axo = xo[v] - mean;
    *(float4*)&a[b * N + ne] = make_float4(axe, acc_e, axo, acc_o);
    float pe = (float)(3.525 * (double)(ne - 512));
    float po = (float)(3.525 * (double)(no - 512));
    float se, cE, so_, cO;
    sincosf(pe, &se, &cE);
    sincosf(po, &so_, &cO);
    *(float4*)&ca[b * N + ne] = make_float4(axe * cE + acc_e * se, acc_e * cE - axe * se,
                                            axo * cO + acc_o * so_, acc_o * cO - axo * so_);

    // ---- fused label MSE (old hilbert_k tail), per-block partial ----
    const float* lab = label + b * 2 * N;
    int mnR = N, mxR = -1, mnI = N, mxI = -1;
#pragma unroll
    for (int k = 0; k < 16; ++k) {
        int n = l + 64 * k;
        float lr = lab[n], li = lab[N + n];
        if (fabsf(lr) > 0.01f) { mnR = min(mnR, n); mxR = max(mxR, n); }
        if (fabsf(li) > 0.01f) { mnI = min(mnI, n); mxI = max(mxI, n); }
    }
    for (int o = 32; o > 0; o >>= 1) {
        mnR = min(mnR, __shfl_down(mnR, o));
        mxR = max(mxR, __shfl_down(mxR, o));
        mnI = min(mnI, __shfl_down(mnI, o));
        mxI = max(mxI, __shfl_down(mxI, o));
    }
    mnR = __shfl(mnR, 0); mxR = __shfl(mxR, 0);
    mnI = __shfl(mnI, 0); mxI = __shfl(mxI, 0);
    int fr   = (mnR == N) ? 0 : mnR;
    int lstR = (mxR < 0) ? (N - 1) : mxR;
    int fi   = (mnI == N) ? 0 : mnI;
    int lstI = (mxI < 0) ? (N - 1) : mxI;
    int first = min(fr, fi), last = max(lstR, lstI);

    float s_lane = 0.f;
    {
        float lr = lab[ne], li = lab[N + ne];
        bool in = (ne >= first) && (ne < last);
        float pm = in ? 10.f : 1.f, phm = in ? 1.f : 0.f;
        float dr = axe - lr, di = acc_e - li;
        float dn = (axe * axe + acc_e * acc_e) - (lr * lr + li * li);
        float dp = atan2f(acc_e, axe) - atan2f(li, lr);
        s_lane += (dr * dr + di * di + dn * dn) * pm + dp * dp * phm;

        lr = lab[no]; li = lab[N + no];
        in = (no >= first) && (no < last);
        pm = in ? 10.f : 1.f; phm = in ? 1.f : 0.f;
        dr = axo - lr; di = acc_o - li;
        dn = (axo * axo + acc_o * acc_o) - (lr * lr + li * li);
        dp = atan2f(acc_o, axo) - atan2f(li, lr);
        s_lane += (dr * dr + di * di + dn * dn) * pm + dp * dp * phm;
    }
    for (int o = 32; o > 0; o >>= 1) s_lane += __shfl_down(s_lane, o);
    if (l == 0) mseP[blk] = s_lane;
}

// ---------------------------------------------------------------------------
// shg_k: REVERT to the round-6 verified structure (best total, 228.8):
// one block = 4 rows, 256 threads, LDS 32768 B, XOR swizzle, block-wide
// stage-1 with x4 row sharing + __syncthreads, tv-prefetch at entry,
// setprio around phases 2-3.  (R7 lesson: removing the barrier costs more
// in duplicated stage-1 loads than the barrier itself.)
// ONE new micro-cut: phase-2 level-B base twiddle derived as level-A
// base^4 (tw(v/64) = tw(v/256)^4) — 2 cmuls replace a sincosf.
// ---------------------------------------------------------------------------
__global__ __launch_bounds__(NT) void shg_k(const cf* __restrict__ a,
                                            const cf* __restrict__ cag,
                                            const float* __restrict__ tref,
                                            float* __restrict__ Praw,
                                            float* __restrict__ Prt,
                                            float* __restrict__ Pmax,
                                            float* __restrict__ Pt,
                                            float* __restrict__ Ptt) {
    __shared__ cf wk[ROWS * N];
    int t = threadIdx.x, blk = blockIdx.x;
    int b = blk >> 8;
    int dg = (blk & 255) << 2;            // delay-indices dg..dg+3
    const cf* arow  = a   + b * N;
    const cf* carow = cag + b * N;

    // ---- tref prefetch (hoisted to entry): 16 loads, consumed in phase 3 ----
    int r3 = t >> 6;                     // row = wave index (phase 2/3)
    int g  = t & 63;                     // 16-block within row
    int bd = b * N + dg + r3;
    int kb = ((g & 3) << 4) | (g & 12) | (g >> 4);   // base-4 digit reversal of g
    const float* trow2 = tref + ((size_t)bd << 10) + kb;
    float tv[16];
#pragma unroll
    for (int u = 0; u < 4; ++u)
#pragma unroll
        for (int m = 0; m < 4; ++m)
            tv[4*u + m] = trow2[(((m + 2) & 3) << 8) | (u << 6)];

    // ---- stage 1 (q=256): twiddle + ca loads shared across all 4 rows ----
    {
        int bt = t;
        cf w1 = twiddle((float)bt * (1.0f / 1024.0f));
        cf w2 = cmul(w1,w1), w3 = cmul(w2,w1);
        cf cv[4];
#pragma unroll
        for (int j = 0; j < 4; ++j) cv[j] = carow[bt + 256*j];   // cav[k] = cv[(k+2)&3]
        int wb = bt ^ (((bt >> 4) & 7) << 1);                    // swizzled slot of bt
#pragma unroll
        for (int r = 0; r < ROWS; ++r) {
            int d = dg + r;
            cf x[4];
#pragma unroll
            for (int k = 0; k < 4; ++k)
                x[k] = cmul(cv[(k + 2) & 3], arow[(bt + 256*k - d) & 1023]);
            cf y0, y1, y2, y3; bfly(x[0],x[1],x[2],x[3],y0,y1,y2,y3);
            cf* w = wk + r * N + wb;
            w[0]   = y0;                  // SW(256k+bt) = 256k + wb
            w[256] = cmul(y1,w1);
            w[512] = cmul(y2,w2);
            w[768] = cmul(y3,w3);
        }
    }
    __syncthreads();

    __builtin_amdgcn_s_setprio(1);
    // ---- phase 2: fused stages q=64 and q=16, fully in registers ----
    {
        int B2 = g >> 4;                  // 256-block within row
        int v  = g & 15;                  // offset within 16-group
        cf* w = wk + r3 * N + B2 * 256;
        cf p[16];
#pragma unroll
        for (int m = 0; m < 16; ++m) p[m] = w[16*m + (v ^ ((m & 7) << 1))];
        // level A: n=256, q=64  (j = v + 16*m0); twiddle chain by tw(1/16)
        cf wA = twiddle((float)v * (1.0f / 256.0f));   // level-A base
        {
            const cf T16 = { 0.923879533f, -0.382683432f };   // tw(16/256)
            cf w1 = wA;
#pragma unroll
            for (int m0 = 0; m0 < 4; ++m0) {
                cf w2 = cmul(w1,w1), w3 = cmul(w2,w1);
                cf y0, y1, y2, y3;
                bfly(p[m0], p[m0+4], p[m0+8], p[m0+12], y0,y1,y2,y3);
                p[m0]    = y0;
                p[m0+4]  = cmul(y1,w1);
                p[m0+8]  = cmul(y2,w2);
                p[m0+12] = cmul(y3,w3);
                w1 = cmul(w1, T16);
            }
        }
        // level B: n=64, q=16  (j = v); base = wA^4 = tw(v/64) — no sincos
        {
            cf sA = cmul(wA, wA);
            cf w1 = cmul(sA, sA);
            cf w2 = cmul(w1,w1), w3 = cmul(w2,w1);
#pragma unroll
            for (int s = 0; s < 4; ++s) {
                cf y0, y1, y2, y3;
                bfly(p[4*s], p[4*s+1], p[4*s+2], p[4*s+3], y0,y1,y2,y3);
                p[4*s]   = y0;
                p[4*s+1] = cmul(y1,w1);
                p[4*s+2] = cmul(y2,w2);
                p[4*s+3] = cmul(y3,w3);
            }
        }
#pragma unroll
        for (int m = 0; m < 16; ++m) w[16*m + (v ^ ((m & 7) << 1))] = p[m];
    }
    WSYNC();   // phase2 -> phase3 is wave-local (wave r3 owns row r3)

    // ---- phase 3: in-register 16-pt DFT + accumulate; wave r3 = row r3 ----
    {
        const cf W1 = { 0.923879533f, -0.382683432f};
        const cf W2 = { 0.707106781f, -0.707106781f};
        const cf W3 = { 0.382683432f, -0.923879533f};
        const cf W6 = {-0.707106781f, -0.707106781f};
        const cf W9 = {-0.923879533f,  0.382683432f};
        cf* w = wk + r3 * N + 16 * g;
        int X = (g & 7) << 1;            // swizzle XOR for this 16-group (even)
        cf v[16];
#pragma unroll
        for (int j = 0; j < 8; ++j) {    // explicit b128: pairs stay adjacent
            float4 q = *(const float4*)&w[(2*j) ^ X];
            v[2*j]   = make_float2(q.x, q.y);
            v[2*j+1] = make_float2(q.z, q.w);
        }
        cf o[16];
        bfly(v[0], v[4], v[8], v[12], o[0], o[4], o[8],  o[12]);
        { cf y0,y1,y2,y3; bfly(v[1],v[5],v[9], v[13],y0,y1,y2,y3);
          o[1]=y0; o[5]=cmul(y1,W1); o[9]=cmul(y2,W2); o[13]=cmul(y3,W3); }
        { cf y0,y1,y2,y3; bfly(v[2],v[6],v[10],v[14],y0,y1,y2,y3);
          o[2]=y0; o[6]=cmul(y1,W2); o[10]=make_float2(y2.y,-y2.x); o[14]=cmul(y3,W6); }
        { cf y0,y1,y2,y3; bfly(v[3],v[7],v[11],v[15],y0,y1,y2,y3);
          o[3]=y0; o[7]=cmul(y1,W3); o[11]=cmul(y2,W6); o[15]=cmul(y3,W9); }

        float sraw = 0.f, srt = 0.f, mx = 0.f, st = 0.f, stt = 0.f;
#pragma unroll
        for (int u = 0; u < 4; ++u) {
            cf y0, y1, y2, y3;
            bfly(o[4*u], o[4*u+1], o[4*u+2], o[4*u+3], y0, y1, y2, y3);
            cf ys[4] = {y0, y1, y2, y3};
#pragma unroll
            for (int m = 0; m < 4; ++m) {
                float m2 = ys[m].x * ys[m].x + ys[m].y * ys[m].y;
                float tvv = tv[4*u + m];
                sraw += m2;
                srt += m2 * tvv;
                mx = fmaxf(mx, m2);
                st += tvv;
                stt += tvv * tvv;
            }
        }
        __builtin_amdgcn_s_setprio(0);
        // full-wave reduction: wave r3 covers g = 0..63 = entire row r3
        for (int o_ = 32; o_ > 0; o_ >>= 1) {
            sraw += __shfl_down(sraw, o_);
            srt  += __shfl_down(srt, o_);
            mx    = fmaxf(mx, __shfl_down(mx, o_));
            st   += __shfl_down(st, o_);
            stt  += __shfl_down(stt, o_);
        }
        if (g == 0) {
            Praw[bd] = sraw; Prt[bd] = srt; Pmax[bd] = mx; Pt[bd] = st; Ptt[bd] = stt;
        }
    }
}

// ---------------------------------------------------------------------------
// loss_k: per batch — frog from row partials + mseP (8 deterministic partials)
// -> atomic mean.  (unchanged)
// ---------------------------------------------------------------------------
__global__ __launch_bounds__(256) void loss_k(const float* __restrict__ Praw,
                                              const float* __restrict__ Prt,
                                              const float* __restrict__ Pmax,
                                              const float* __restrict__ Pt,
                                              const float* __restrict__ Ptt,
                                              const float* __restrict__ mseP,
                                              float* __restrict__ out) {
    __shared__ float rbuf[4][8];
    int tid = threadIdx.x, b = blockIdx.x;
    int w = tid >> 6, lane = tid & 63;
    float sr = 0.f, srt = 0.f, mx = 0.f, st = 0.f, stt = 0.f;
    for (int i = tid; i < N; i += 256) {
        int idx = b * N + i;
        sr += Praw[idx]; srt += Prt[idx]; mx = fmaxf(mx, Pmax[idx]);
        st += Pt[idx];   stt += Ptt[idx];
    }
    for (int o = 32; o > 0; o >>= 1) {
        sr  += __shfl_down(sr, o);
        srt += __shfl_down(srt, o);
        mx   = fmaxf(mx, __shfl_down(mx, o));
        st  += __shfl_down(st, o);
        stt += __shfl_down(stt, o);
    }
    if (lane == 0) {
        rbuf[w][0] = sr; rbuf[w][1] = srt; rbuf[w][2] = mx;
        rbuf[w][3] = st; rbuf[w][4] = stt;
    }
    __syncthreads();
    if (tid == 0) {
        float A0 = 0.f, A1 = 0.f, A2 = 0.f, A3 = 0.f, A4 = 0.f;
        for (int i = 0; i < 4; ++i) {
            A0 += rbuf[i][0]; A1 += rbuf[i][1]; A2 = fmaxf(A2, rbuf[i][2]);
            A3 += rbuf[i][3]; A4 += rbuf[i][4];
        }
        float mu = (A1 / A2) / A4;
        float diff = A0 / A2 - mu * A3;
        float frog = fabsf(diff) * (1.f / (float)N);
        float ms = 0.f;
        for (int k = 0; k < 8; ++k) ms += mseP[b * 8 + k];
        ms *= (1.f / (float)N) * 0.25f;
        atomicAdd(out, (ms + frog) * (1.f / (float)BATCH));
    }
}

extern "C" void kernel_launch(void* const* d_in, const int* in_sizes, int n_in,
                              void* d_out, int out_size, void* d_ws, size_t ws_size,
                              hipStream_t stream) {
    (void)in_sizes; (void)n_in; (void)out_size; (void)ws_size;
    const float* pred  = (const float*)d_in[0];
    const float* label = (const float*)d_in[1];
    const float* shg   = (const float*)d_in[2];
    float* out = (float*)d_out;

    char* ws = (char*)d_ws;
    cf* a   = (cf*)ws;
    cf* ca  = a + (size_t)BATCH * N;
    float* mseP = (float*)(ca + (size_t)BATCH * N);      // BATCH*8 partials
    float* P = mseP + BATCH * 8;
    float* Praw = P;
    float* Prt  = P + (size_t)BATCH * N;
    float* Pmax = P + 2 * (size_t)BATCH * N;
    float* Pt   = P + 3 * (size_t)BATCH * N;
    float* Ptt  = P + 4 * (size_t)BATCH * N;

    hipMemsetAsync(d_out, 0, sizeof(float), stream);
    hconv_k<<<BATCH * 8, 64, 0, stream>>>(pred, label, a, ca, mseP);
    shg_k<<<BATCH * 256, NT, 0, stream>>>(a, ca, shg, Praw, Prt, Pmax, Pt, Ptt);
    loss_k<<<BATCH, 256, 0, stream>>>(Praw, Prt, Pmax, Pt, Ptt, mseP, out);
}